// Round 2
// baseline (1363.718 us; speedup 1.0000x reference)
//
#include <hip/hip_runtime.h>
#include <hip/hip_bf16.h>

// ---------------- problem constants ----------------
#define NROWS   32768      // B*S = 8*4096
#define DIN     2048
#define DOUT    2048
#define RANKS   64
#define NGROUP  32         // R / RP
#define TOPK    8
#define SCALING 2.0f       // lora_alpha(16) / activate_r(8)

typedef unsigned short ushort_t;
using bf16x8 = __attribute__((ext_vector_type(8))) short;
using f32x4  = __attribute__((ext_vector_type(4))) float;

__device__ __forceinline__ unsigned short f32_to_bf16_rne(float f) {
    union { float f; unsigned int u; } a; a.f = f;
    unsigned int r = a.u + 0x7FFFu + ((a.u >> 16) & 1u);
    return (unsigned short)(r >> 16);
}
__device__ __forceinline__ float bf16_bits_to_f32(unsigned short h) {
    union { unsigned int u; float f; } b; b.u = ((unsigned int)h) << 16;
    return b.f;
}
__device__ __forceinline__ void bf16split(float v, unsigned short& hi, unsigned short& lo) {
    hi = f32_to_bf16_rne(v);
    float r = v - bf16_bits_to_f32(hi);
    lo = f32_to_bf16_rne(r);
}
__device__ __forceinline__ void bf16split4(const float4& v, ushort4& h, ushort4& l) {
    unsigned short h0,h1,h2,h3,l0,l1,l2,l3;
    bf16split(v.x,h0,l0); bf16split(v.y,h1,l1);
    bf16split(v.z,h2,l2); bf16split(v.w,h3,l3);
    h = make_ushort4(h0,h1,h2,h3); l = make_ushort4(l0,l1,l2,l3);
}

// async global->LDS, 16B per lane; LDS dest is wave-uniform base (+lane*16 by HW)
__device__ __forceinline__ void gll16(const ushort_t* g, ushort_t* l) {
    __builtin_amdgcn_global_load_lds(
        (const __attribute__((address_space(1))) unsigned int*)g,
        (__attribute__((address_space(3))) unsigned int*)l,
        16, 0, 0);
}

// Split layout: row-major, per 32-k block: 64 ushorts = [hi k0..31 | lo k0..31].
// Row stride (ushorts): DIN*2=4096 for x/W, RANKS*2=128 for gmid/Bw.

// ================= Kernel 0: pre-split W, Bw =================
__global__ __launch_bounds__(256) void preconv_kernel(
    const float* __restrict__ W, const float* __restrict__ Bw,
    ushort_t* __restrict__ Wsp, ushort_t* __restrict__ Bwsp)
{
    const int nW = DOUT * DIN / 4;
    const int nB = DOUT * RANKS / 4;
    for (int i = blockIdx.x * blockDim.x + threadIdx.x; i < nW + nB;
         i += gridDim.x * blockDim.x) {
        if (i < nW) {
            int e = i * 4; int row = e >> 11; int k = e & 2047;
            float4 v = *(const float4*)&W[e];
            ushort4 h, l; bf16split4(v, h, l);
            size_t base = (size_t)row * 4096 + (size_t)(k >> 5) * 64 + (k & 31);
            *(ushort4*)&Wsp[base]      = h;
            *(ushort4*)&Wsp[base + 32] = l;
        } else {
            int e = (i - nW) * 4; int row = e >> 6; int k = e & 63;
            float4 v = *(const float4*)&Bw[e];
            ushort4 h, l; bf16split4(v, h, l);
            size_t base = (size_t)row * 128 + (size_t)(k >> 5) * 64 + (k & 31);
            *(ushort4*)&Bwsp[base]      = h;
            *(ushort4*)&Bwsp[base + 32] = l;
        }
    }
}

// ================= Kernel 1: router + mid + top-k gating (+x pre-split) =================
#define K1_ROWS 64
#define K1_KC   64
#define K1_LS   68
#define NOUT    96

template<bool PRE>
__global__ __launch_bounds__(256) void router_mid_kernel(
    const float* __restrict__ x, const float* __restrict__ routerW,
    const float* __restrict__ A, const float* __restrict__ biases,
    ushort_t* __restrict__ gmidsp, ushort_t* __restrict__ Xsp)
{
    __shared__ __align__(16) float smem[K1_ROWS * K1_LS + NOUT * K1_LS]; // 43.5 KB
    float* xt = smem;
    float* wt = smem + K1_ROWS * K1_LS;

    const int t  = threadIdx.x;
    const int n0 = blockIdx.x * K1_ROWS;
    const int r0 = (t >> 4) * 4;
    const int o0 = (t & 15) * 6;

    float acc[4][6];
#pragma unroll
    for (int i = 0; i < 4; ++i)
#pragma unroll
        for (int j = 0; j < 6; ++j) acc[i][j] = 0.f;

    for (int kc = 0; kc < DIN; kc += K1_KC) {
#pragma unroll
        for (int p = 0; p < 4; ++p) {
            int row = p * 16 + (t >> 4);
            int c4  = (t & 15) * 4;
            float4 v = *(const float4*)&x[(size_t)(n0 + row) * DIN + kc + c4];
            *(float4*)&xt[row * K1_LS + c4] = v;
            if (PRE) {  // fused x pre-split: each element split exactly once
                int k2 = kc + c4;
                ushort4 h, l; bf16split4(v, h, l);
                size_t xb = (size_t)(n0 + row) * 4096 + (size_t)(k2 >> 5) * 64 + (k2 & 31);
                *(ushort4*)&Xsp[xb]      = h;
                *(ushort4*)&Xsp[xb + 32] = l;
            }
        }
#pragma unroll
        for (int p = 0; p < 6; ++p) {
            int row = p * 16 + (t >> 4);
            int c4  = (t & 15) * 4;
            const float* src = (row < NGROUP) ? &routerW[(size_t)row * DIN]
                                              : &A[(size_t)(row - NGROUP) * DIN];
            *(float4*)&wt[row * K1_LS + c4] = *(const float4*)&src[kc + c4];
        }
        __syncthreads();

#pragma unroll 4
        for (int kk = 0; kk < K1_KC; kk += 4) {
            float4 xv[4], wv[6];
#pragma unroll
            for (int i = 0; i < 4; ++i)
                xv[i] = *(const float4*)&xt[(r0 + i) * K1_LS + kk];
#pragma unroll
            for (int j = 0; j < 6; ++j)
                wv[j] = *(const float4*)&wt[(o0 + j) * K1_LS + kk];
#pragma unroll
            for (int i = 0; i < 4; ++i)
#pragma unroll
                for (int j = 0; j < 6; ++j) {
                    acc[i][j] += xv[i].x * wv[j].x;
                    acc[i][j] += xv[i].y * wv[j].y;
                    acc[i][j] += xv[i].z * wv[j].z;
                    acc[i][j] += xv[i].w * wv[j].w;
                }
        }
        __syncthreads();
    }

    float* dots = smem;  // tiles dead; 64*96 floats fits
#pragma unroll
    for (int i = 0; i < 4; ++i)
#pragma unroll
        for (int j = 0; j < 6; ++j)
            dots[(r0 + i) * NOUT + (o0 + j)] = acc[i][j];
    __syncthreads();

    const int wid  = t >> 6;
    const int lane = t & 63;
    const float bia = biases[lane];
    for (int rr = wid; rr < K1_ROWS; rr += 4) {
        float glog  = dots[rr * NOUT + (lane >> 1)];
        float sig   = 1.0f / (1.0f + expf(-glog));
        float logit = sig + bia;
        float midv  = dots[rr * NOUT + 32 + lane];

        float mval = logit;
        int   sel  = 0;
        float ssum = 0.f;
#pragma unroll
        for (int it = 0; it < TOPK; ++it) {
            float v  = mval;
            int   ix = lane;
#pragma unroll
            for (int off = 1; off < 64; off <<= 1) {
                float ov = __shfl_xor(v, off);
                int   oi = __shfl_xor(ix, off);
                if (ov > v || (ov == v && oi < ix)) { v = ov; ix = oi; }
            }
            ssum += v;
            if (lane == ix) { sel = 1; mval = -1e30f; }
        }
        float gate = sel ? (logit / ssum) * (float)TOPK : 0.f;
        float gv   = midv * gate * SCALING;
        unsigned short gh, gl; bf16split(gv, gh, gl);
        size_t gb = (size_t)(n0 + rr) * 128 + (size_t)(lane >> 5) * 64 + (lane & 31);
        gmidsp[gb]      = gh;
        gmidsp[gb + 32] = gl;
    }
}

// ================= Kernel 2: fused bf16x3 GEMM  out = x.W^T + gmid.Bw^T =================
// 128x128 tile, 66 K-steps (64 x 32k main + 2 x 32rank lora), m97 structure:
// global_load_lds(16B) staging, single-buffered LDS, 2 barriers/step.
// LDS tile [128 rows][64 bf16] (hi slots 0-3 | lo slots 4-7), 128-B rows,
// swizzle slot^=(row&7): applied on the GLOBAL source for staging (LDS linear)
// and on the ds_read address (rule #21 both-sides pair). 2 lanes/bank-quad = free.
#define BM 128
#define BN 128
#define KSTEPS 66

template<bool PRE>
__global__ __launch_bounds__(256) void fused_gemm_kernel(
    const float* __restrict__ x, const ushort_t* __restrict__ Xsp,
    const ushort_t* __restrict__ gmidsp,
    const ushort_t* __restrict__ Wsp, const ushort_t* __restrict__ Bwsp,
    float* __restrict__ out)
{
    __shared__ __align__(16) ushort_t As[BM * 64];  // 16 KB
    __shared__ __align__(16) ushort_t Bs[BN * 64];  // 16 KB

    // m204 bijective XCD swizzle (nwg=4096, %8==0); col-fast within chunk
    const int orig = blockIdx.x;
    const int q    = gridDim.x >> 3;
    const int wg   = (orig & 7) * q + (orig >> 3);
    const int cbase = (wg & 15) * BN;
    const int rbase = (wg >> 4) * BM;

    const int t = threadIdx.x;
    const int w = t >> 6, lane = t & 63;
    const int wr = w >> 1, wc = w & 1;
    const int lr = lane & 15, lk = lane >> 4;

    const int rowInChunk = lane >> 3;                 // 0..7
    const int slotSrc    = (lane & 7) ^ rowInChunk;   // pre-swizzled source slot

    f32x4 acc[4][4];
#pragma unroll
    for (int i = 0; i < 4; ++i)
#pragma unroll
        for (int j = 0; j < 4; ++j) acc[i][j] = f32x4{0.f, 0.f, 0.f, 0.f};

    auto stageB = [&](int s) {
        const ushort_t* Bsrc; size_t bstr; int k0;
        if (s < 64) { Bsrc = Wsp;  bstr = 4096; k0 = s * 64; }
        else        { Bsrc = Bwsp; bstr = 128;  k0 = (s - 64) * 64; }
#pragma unroll
        for (int c = 0; c < 4; ++c) {
            int chunk = w * 4 + c;                    // wave w stages rows w*32..+31
            int row   = chunk * 8 + rowInChunk;
            gll16(Bsrc + (size_t)(cbase + row) * bstr + k0 + slotSrc * 8,
                  &Bs[chunk * 512]);
        }
    };
    auto stageA_pre = [&](int s) {
        const ushort_t* Asrc; size_t astr; int k0;
        if (s < 64) { Asrc = Xsp;    astr = 4096; k0 = s * 64; }
        else        { Asrc = gmidsp; astr = 128;  k0 = (s - 64) * 64; }
#pragma unroll
        for (int c = 0; c < 4; ++c) {
            int chunk = w * 4 + c;
            int row   = chunk * 8 + rowInChunk;
            gll16(Asrc + (size_t)(rbase + row) * astr + k0 + slotSrc * 8,
                  &As[chunk * 512]);
        }
    };
    auto stageA_reg = [&](int s) {   // fallback: split x on the fly, swizzled ds_write
        const int srow = t >> 3;     // 0..31
        const int sq   = t & 7;      // k-quad 0..7
#pragma unroll
        for (int p = 0; p < 4; ++p) {
            int row = p * 32 + srow;
            float4 v = *(const float4*)&x[(size_t)(rbase + row) * DIN + s * 32 + sq * 4];
            ushort4 h, l; bf16split4(v, h, l);
            int shi = (sq >> 1) ^ (row & 7);
            int slo = ((sq >> 1) + 4) ^ (row & 7);
            int pos = (sq & 1) * 4;
            *(ushort4*)&As[row * 64 + shi * 8 + pos] = h;
            *(ushort4*)&As[row * 64 + slo * 8 + pos] = l;
        }
    };
    auto compute = [&]() {
        bf16x8 ah[4], al[4], bh[4], bl[4];
#pragma unroll
        for (int f = 0; f < 4; ++f) {
            int ar = wr * 64 + f * 16 + lr;
            ah[f] = *(const bf16x8*)&As[ar * 64 + ((lk       ^ (ar & 7)) * 8)];
            al[f] = *(const bf16x8*)&As[ar * 64 + (((lk + 4) ^ (ar & 7)) * 8)];
            int br = wc * 64 + f * 16 + lr;
            bh[f] = *(const bf16x8*)&Bs[br * 64 + ((lk       ^ (br & 7)) * 8)];
            bl[f] = *(const bf16x8*)&Bs[br * 64 + (((lk + 4) ^ (br & 7)) * 8)];
        }
#pragma unroll
        for (int i = 0; i < 4; ++i)
#pragma unroll
            for (int j = 0; j < 4; ++j) {
                acc[i][j] = __builtin_amdgcn_mfma_f32_16x16x32_bf16(ah[i], bh[j], acc[i][j], 0, 0, 0);
                acc[i][j] = __builtin_amdgcn_mfma_f32_16x16x32_bf16(ah[i], bl[j], acc[i][j], 0, 0, 0);
                acc[i][j] = __builtin_amdgcn_mfma_f32_16x16x32_bf16(al[i], bh[j], acc[i][j], 0, 0, 0);
            }
    };

    for (int s = 0; s < KSTEPS; ++s) {
        stageB(s);
        if (PRE || s >= 64) stageA_pre(s); else stageA_reg(s);
        __syncthreads();   // drains vmcnt+lgkmcnt before compute
        compute();
        __syncthreads();   // protect LDS before next stage
    }

    // epilogue: C/D col=lane&15, row=(lane>>4)*4+e  [m89-verified]
#pragma unroll
    for (int i = 0; i < 4; ++i)
#pragma unroll
        for (int j = 0; j < 4; ++j)
#pragma unroll
            for (int e = 0; e < 4; ++e) {
                int row = rbase + wr * 64 + i * 16 + lk * 4 + e;
                int col = cbase + wc * 64 + j * 16 + lr;
                out[(size_t)row * DOUT + col] = acc[i][j][e];
            }
}

// ================= launch =================
extern "C" void kernel_launch(void* const* d_in, const int* in_sizes, int n_in,
                              void* d_out, int out_size, void* d_ws, size_t ws_size,
                              hipStream_t stream) {
    (void)in_sizes; (void)n_in; (void)out_size;
    const float* x       = (const float*)d_in[0];
    const float* baseW   = (const float*)d_in[1];
    const float* routerW = (const float*)d_in[2];
    const float* A       = (const float*)d_in[3];
    const float* Bw      = (const float*)d_in[4];
    const float* biases  = (const float*)d_in[5];
    float* out = (float*)d_out;

    char* p = (char*)d_ws;
    ushort_t* Wsp    = (ushort_t*)p;               //  16,777,216 B
    ushort_t* Bwsp   = (ushort_t*)(p + 16777216);  //     524,288 B
    ushort_t* gmidsp = (ushort_t*)(p + 17301504);  //   8,388,608 B
    ushort_t* Xsp    = (ushort_t*)(p + 25690112);  // 268,435,456 B (PRE only)
    const bool pre = ws_size >= 25690112ull + 268435456ull;

    hipLaunchKernelGGL(preconv_kernel, dim3(1024), dim3(256), 0, stream,
                       baseW, Bw, Wsp, Bwsp);
    if (pre) {
        hipLaunchKernelGGL((router_mid_kernel<true>), dim3(NROWS / K1_ROWS), dim3(256), 0,
                           stream, x, routerW, A, biases, gmidsp, Xsp);
        hipLaunchKernelGGL((fused_gemm_kernel<true>), dim3((NROWS / BM) * (DOUT / BN)),
                           dim3(256), 0, stream, x, Xsp, gmidsp, Wsp, Bwsp, out);
    } else {
        hipLaunchKernelGGL((router_mid_kernel<false>), dim3(NROWS / K1_ROWS), dim3(256), 0,
                           stream, x, routerW, A, biases, gmidsp, Xsp);
        hipLaunchKernelGGL((fused_gemm_kernel<false>), dim3((NROWS / BM) * (DOUT / BN)),
                           dim3(256), 0, stream, x, Xsp, gmidsp, Wsp, Bwsp, out);
    }
}